// Round 5
// baseline (255.686 us; speedup 1.0000x reference)
//
#include <hip/hip_runtime.h>
#include <stdint.h>

// mean(|x|) > 1.0 over D=128  <=>  sum(|x|) > 128.0
// Rows with bf16-estimated sum|x| > FLAG_THRESH get an exact-fp32 in-wave
// recompute (covers all branch-1 rows plus borderline rows; ~35 of 262144).
#define FLAG_THRESH 127.0f

typedef short bfrag __attribute__((ext_vector_type(8)));   // 8 bf16 (4 VGPRs)
typedef float floatx4 __attribute__((ext_vector_type(4))); // MFMA acc
typedef int intx4 __attribute__((ext_vector_type(4)));

__device__ __forceinline__ unsigned bf16pk(float a, float b) {  // RNE pack
    unsigned ua = __float_as_uint(a), ub = __float_as_uint(b);
    ua = (ua + 0x7fffu + ((ua >> 16) & 1u)) >> 16;
    ub = (ub + 0x7fffu + ((ub >> 16) & 1u)) & 0xffff0000u;
    return ua | ub;
}
__device__ __forceinline__ unsigned short bf16s(float a) {      // RNE scalar
    unsigned ua = __float_as_uint(a);
    return (unsigned short)((ua + 0x7fffu + ((ua >> 16) & 1u)) >> 16);
}
__device__ __forceinline__ bfrag mkfrag(unsigned a, unsigned b, unsigned c, unsigned d) {
    intx4 v = {(int)a, (int)b, (int)c, (int)d};
    return __builtin_bit_cast(bfrag, v);
}
// lgkmcnt(0)-only wait (vmcnt/expcnt bits all-ones), wave-local
__device__ __forceinline__ void lds_fence_wave() {
    __builtin_amdgcn_wave_barrier();
    __builtin_amdgcn_s_waitcnt(0xc07f);
    __builtin_amdgcn_wave_barrier();
}

// Counted vmcnt waits (gfx9 encoding: vm[3:0]=bits3:0, vm[5:4]=bits15:14,
// exp=bits6:4 (7=ignore), lgkm=bits11:8 (F=ignore)).
#define VM0  0x0F70   // vmcnt(0)
#define VM8  0x0F78   // vmcnt(8)
#define VM16 0x4F70   // vmcnt(16)
#define WAITVM(imm) do {                       \
    asm volatile("" ::: "memory");             \
    __builtin_amdgcn_s_waitcnt(imm);           \
    asm volatile("" ::: "memory");             \
    __builtin_amdgcn_sched_barrier(0);         \
} while (0)

// 16-B direct global->LDS DMA (no VGPR destination, tracked by vmcnt).
// LDS dest is wave-uniform base + lane*16; global src is per-lane.
__device__ __forceinline__ void gl16(const void* gsrc, void* ldst) {
    __builtin_amdgcn_global_load_lds(
        (const __attribute__((address_space(1))) unsigned int*)gsrc,
        (__attribute__((address_space(3))) unsigned int*)ldst, 16, 0, 0);
}

// ---------------------------------------------------------------------------
// SINGLE-DISPATCH kernel, DMA-pipelined reads.
//
// Evidence: r4's L3-warm dispatch (FETCH~0) ran at IDENTICAL duration ->
// not HBM-read-bound. Per-CU byte rate ~9-12 GB/s across 8/16/28 waves/CU
// (copy ceiling ~24.6) with all pipes <10% -> waves sit in vmcnt stalls;
// the register-prefetch pipeline keeps memory in flight only a fraction of
// each iteration. This version: x-tiles staged by global_load_lds (width 16,
// zero VGPR cost), per-wave double buffer, counted vmcnt(16) so the next
// tile's loads + previous tile's stores stay in flight across the whole
// compute phase. LDS reads use XOR swizzle (row&7)<<4, applied to the
// GLOBAL source address (gload_lds writes linearly) and to the ds_read
// address -> conflict-free b128 fragment reads.
//
// Store path = r0's proven one: always store approx in fragment layout,
// rare rows overwritten exactly afterwards (vmcnt(0) drain first, rare only).
//
// History: r0 87us 2.34TB/s | r1 VGPR-squeeze 111us | r2 = r0 | r3 fused
// +store-dup inflation 97us | r4 coalesced stores: clean WRITE, 93us (null).
// ---------------------------------------------------------------------------
__global__ __launch_bounds__(512, 2)
void dyn_main(const float* __restrict__ x, const float* __restrict__ W1,
              const float* __restrict__ b1, const float* __restrict__ W2,
              const float* __restrict__ b2, const float* __restrict__ Wf,
              const float* __restrict__ bf, float* __restrict__ out,
              int ntiles)
{
    __shared__ __align__(16) float xbuf[8][2][2048]; // 8 waves x 2 bufs x 8KB
    __shared__ __align__(16) short w2f[8][64][8];    // [ks*2+nb][lane][j]
    __shared__ __align__(16) short wff[8][64][8];    // [mb][lane][j]
    __shared__ __align__(16) float bfl[128];
    __shared__ __align__(16) short hbuf[8][16 * 40]; // per-wave H, stride 40
    __shared__ __align__(16) float hh[8][64];        // rare path: exact hidden

    const int tid  = threadIdx.x;
    const int wave = tid >> 6, lane = tid & 63;
    const int l15  = lane & 15, q = lane >> 4;

    // ---- stage weights into LDS (once per block) ----
    for (int idx = tid; idx < 4096; idx += 512) {
        const int j = idx & 7, ln = (idx >> 3) & 63, blk = idx >> 9;
        const int ks = blk >> 1, nb = blk & 1;
        const int u = nb * 16 + (ln & 15);
        const int k = ks * 32 + ((ln >> 4) << 3) + j;
        ((short*)w2f)[idx] = (short)bf16s(W2[u * 128 + k]);
        const int d = blk * 16 + (ln & 15);
        const int c = ((ln >> 4) << 3) + j;
        ((short*)wff)[idx] = (short)bf16s(Wf[d * 64 + c]);
    }
    for (int i = tid; i < 128; i += 512) bfl[i] = bf[i];
    const float b2r0 = b2[l15], b2r1 = b2[16 + l15];
    __syncthreads();

    // ones-column B fragment: B[k][n] = (n==0) ? 1.0bf16 : 0
    const unsigned ov = (l15 == 0) ? 0x3f803f80u : 0u;
    const bfrag onesf = mkfrag(ov, ov, ov, ov);

    const int wid = blockIdx.x * 8 + wave;
    const int wstride = gridDim.x * 8;

    // Issue one 8-KB tile (8 x gload_lds, 1 KB each). LDS layout linear
    // row-major; global source pre-swizzled by ((row&7)<<4) so that the
    // swizzled ds_read below is the inverse permutation.
#define ISSUE_TILE(t, b) do {                                              \
        const char* gb_ = (const char*)(x + (long long)(t) * 2048);        \
        char* lb_ = (char*)&xbuf[wave][(b)][0];                            \
        _Pragma("unroll")                                                  \
        for (int j_ = 0; j_ < 8; ++j_) {                                   \
            const int off_ = j_ * 1024 + lane * 16;                        \
            const int src_ = off_ ^ (((off_ >> 9) & 7) << 4);              \
            gl16(gb_ + src_, lb_ + j_ * 1024);                             \
        }                                                                  \
        __builtin_amdgcn_sched_barrier(0);                                 \
    } while (0)

    long long cur = wid;
    bool more = cur < ntiles;
    int bufc = 0;
    if (more) ISSUE_TILE(cur, 0);
    bool first = true;

    while (more) {
        const long long nxt = cur + wstride;
        const bool hasnxt = nxt < ntiles;
        if (hasnxt) ISSUE_TILE(nxt, bufc ^ 1);

        // Wait for current tile's DMA. In-flight queue (oldest->newest):
        // L(i)[8], S(i-1)[8 if not first], L(i+1)[8 if hasnxt]. vmcnt counted
        // so stores + next loads stay outstanding (in-order retirement).
        if (first) { if (hasnxt) WAITVM(VM8);  else WAITVM(VM0); }
        else       { if (hasnxt) WAITVM(VM16); else WAITVM(VM8); }

        const char* xb = (const char*)&xbuf[wave][bufc][0];
        const int sw = (l15 & 7) << 4;

        // ---- stage 1: fragments straight from swizzled LDS ----
        floatx4 a0 = {0.f, 0.f, 0.f, 0.f}, a1 = a0, asum = a0;
        #pragma unroll
        for (int ks = 0; ks < 4; ++ks) {
            const int g0 = (l15 << 9) + (ks << 7) + (q << 5);
            const floatx4 p = *(const floatx4*)(xb + (g0 ^ sw));
            const floatx4 r = *(const floatx4*)(xb + ((g0 + 16) ^ sw));
            const unsigned u0 = bf16pk(p[0], p[1]), u1 = bf16pk(p[2], p[3]);
            const unsigned u2 = bf16pk(r[0], r[1]), u3 = bf16pk(r[2], r[3]);
            const bfrag af = mkfrag(u0, u1, u2, u3);
            const bfrag aa = mkfrag(u0 & 0x7fff7fffu, u1 & 0x7fff7fffu,
                                    u2 & 0x7fff7fffu, u3 & 0x7fff7fffu);
            const bfrag w0 = *(const bfrag*)&w2f[ks * 2 + 0][lane][0];
            const bfrag w1 = *(const bfrag*)&w2f[ks * 2 + 1][lane][0];
            a0   = __builtin_amdgcn_mfma_f32_16x16x32_bf16(af, w0, a0, 0, 0, 0);
            a1   = __builtin_amdgcn_mfma_f32_16x16x32_bf16(af, w1, a1, 0, 0, 0);
            asum = __builtin_amdgcn_mfma_f32_16x16x32_bf16(aa, onesf, asum, 0, 0, 0);
        }

        // ---- flag suspicious rows: wave-uniform 16-bit row mask ----
        unsigned rowmask = 0;
        #pragma unroll
        for (int reg = 0; reg < 4; ++reg) {
            const unsigned long long bm =
                __ballot(l15 == 0 && asum[reg] > FLAG_THRESH);
            rowmask |= (unsigned)( bm        & 1ull) << (0 + reg);
            rowmask |= (unsigned)((bm >> 16) & 1ull) << (4 + reg);
            rowmask |= (unsigned)((bm >> 32) & 1ull) << (8 + reg);
            rowmask |= (unsigned)((bm >> 48) & 1ull) << (12 + reg);
        }

        // H = relu(S + b2) -> LDS bf16.  C-layout: row=q*4+reg, col=nb*16+l15
        short* hb = &hbuf[wave][0];
        #pragma unroll
        for (int reg = 0; reg < 4; ++reg) {
            const int row = q * 4 + reg;
            hb[row * 40 + l15]      = (short)bf16s(fmaxf(a0[reg] + b2r0, 0.f));
            hb[row * 40 + 16 + l15] = (short)bf16s(fmaxf(a1[reg] + b2r1, 0.f));
        }

        lds_fence_wave();

        // ---- stage 2 (transposed): A = Wf slice, B = H^T ----
        const bfrag hfrag = *(const bfrag*)&hb[l15 * 40 + q * 8];
        floatx4 o[8];
        #pragma unroll
        for (int mb = 0; mb < 8; ++mb) o[mb] = (floatx4){0.f, 0.f, 0.f, 0.f};
        #pragma unroll
        for (int mb = 0; mb < 8; ++mb) {
            const bfrag wfr = *(const bfrag*)&wff[mb][lane][0];
            o[mb] = __builtin_amdgcn_mfma_f32_16x16x32_bf16(wfr, hfrag, o[mb], 0, 0, 0);
        }

        // ---- store approx result for ALL rows (r0's proven path) ----
        // C-layout: lane holds out[row = cur*16 + l15][d = mb*16 + q*4 + reg]
        float* obase = out + (cur * 16 + l15) * 128 + q * 4;
        #pragma unroll
        for (int mb = 0; mb < 8; ++mb) {
            const floatx4 bv = *(const floatx4*)&bfl[mb * 16 + q * 4];
            const floatx4 v = o[mb] + bv;
            *(floatx4*)(obase + mb * 16) = v;
        }

        // ---- rare path (~35/16384 tiles): exact fp32 recompute + overwrite.
        // Reads the exact fp32 row from the staged LDS tile (swizzled).
        // Numerics identical to the original fixup kernel (same op order).
        if (__builtin_expect(rowmask != 0, 0)) {
            WAITVM(VM0);   // approx stores committed before exact overwrite
            unsigned mm = rowmask;
            while (mm) {
                const int r = (int)__builtin_ctz(mm); mm &= mm - 1;
                const int swr = (r & 7) << 4;
                const float2 xv =
                    *(const float2*)(xb + (((r << 9) + lane * 8) ^ swr));
                float s = fabsf(xv.x) + fabsf(xv.y);
                #pragma unroll
                for (int d = 1; d < 64; d <<= 1) s += __shfl_xor(s, d);
                float hv = 0.f;
                if (s > 128.0f) {                    // branch 1: 64 units of W1
                    float a = 0.f;
                    for (int k = 0; k < 128; k += 4) {
                        const float4 qq = *(const float4*)(
                            xb + (((r << 9) + (k << 2)) ^ swr));
                        const float4 wv = *(const float4*)&W1[lane * 128 + k];
                        a = fmaf(qq.x, wv.x, a); a = fmaf(qq.y, wv.y, a);
                        a = fmaf(qq.z, wv.z, a); a = fmaf(qq.w, wv.w, a);
                    }
                    hv = fmaxf(a + b1[lane], 0.f);
                } else if (lane < 32) {              // branch 2: 32 units of W2
                    float a = 0.f;
                    for (int k = 0; k < 128; k += 4) {
                        const float4 qq = *(const float4*)(
                            xb + (((r << 9) + (k << 2)) ^ swr));
                        const float4 wv = *(const float4*)&W2[lane * 128 + k];
                        a = fmaf(qq.x, wv.x, a); a = fmaf(qq.y, wv.y, a);
                        a = fmaf(qq.z, wv.z, a); a = fmaf(qq.w, wv.w, a);
                    }
                    hv = fmaxf(a + b2[lane], 0.f);
                }
                hh[wave][lane] = hv;                 // zero-padded for branch 2
                lds_fence_wave();
                #pragma unroll
                for (int jj = 0; jj < 2; ++jj) {
                    const int d = lane + 64 * jj;
                    float a = bf[d];
                    for (int u = 0; u < 64; ++u)
                        a = fmaf(hh[wave][u], Wf[d * 64 + u], a);
                    out[(cur * 16 + r) * 128 + d] = a;
                }
                lds_fence_wave();   // hh reads drained before next row reuse
            }
        }

        lds_fence_wave();   // hfrag/xbuf ds-reads drained before buffer reuse
        first = false; bufc ^= 1; cur = nxt; more = hasnxt;
    }
#undef ISSUE_TILE
}

extern "C" void kernel_launch(void* const* d_in, const int* in_sizes, int n_in,
                              void* d_out, int out_size, void* d_ws, size_t ws_size,
                              hipStream_t stream) {
    const float* x  = (const float*)d_in[0];
    const float* W1 = (const float*)d_in[1];
    const float* b1 = (const float*)d_in[2];
    const float* W2 = (const float*)d_in[3];
    const float* b2 = (const float*)d_in[4];
    const float* Wf = (const float*)d_in[5];
    const float* bf = (const float*)d_in[6];
    float* out = (float*)d_out;
    (void)d_ws; (void)ws_size;

    const int B = in_sizes[0] / 128;   // D = 128
    const int ntiles = B / 16;         // 16384 for B=262144

    // ONE dispatch. 256 blocks x 512 thr = 8 waves/CU (1 block/CU, LDS
    // ~157 KB). Same wave concurrency as the 87-us baseline — the isolated
    // variable is the DMA read pipeline (gload_lds + counted vmcnt).
    hipLaunchKernelGGL(dyn_main, dim3(256), dim3(512), 0, stream,
                       x, W1, b1, W2, b2, Wf, bf, out, ntiles);
}

// Round 7
// 255.027 us; speedup vs baseline: 1.0026x; 1.0026x over previous
//
#include <hip/hip_runtime.h>
#include <stdint.h>

// mean(|x|) > 1.0 over D=128  <=>  sum(|x|) > 128.0
// Rows with bf16-estimated sum|x| > FLAG_THRESH get an exact-fp32 in-wave
// recompute (covers all branch-1 rows plus borderline rows; ~35 of 262144).
#define FLAG_THRESH 127.0f

typedef short bfrag __attribute__((ext_vector_type(8)));   // 8 bf16 (4 VGPRs)
typedef float floatx4 __attribute__((ext_vector_type(4))); // MFMA acc
typedef int intx4 __attribute__((ext_vector_type(4)));

__device__ __forceinline__ unsigned bf16pk(float a, float b) {  // RNE pack
    unsigned ua = __float_as_uint(a), ub = __float_as_uint(b);
    ua = (ua + 0x7fffu + ((ua >> 16) & 1u)) >> 16;
    ub = (ub + 0x7fffu + ((ub >> 16) & 1u)) & 0xffff0000u;
    return ua | ub;
}
__device__ __forceinline__ unsigned short bf16s(float a) {      // RNE scalar
    unsigned ua = __float_as_uint(a);
    return (unsigned short)((ua + 0x7fffu + ((ua >> 16) & 1u)) >> 16);
}
__device__ __forceinline__ bfrag mkfrag(unsigned a, unsigned b, unsigned c, unsigned d) {
    intx4 v = {(int)a, (int)b, (int)c, (int)d};
    return __builtin_bit_cast(bfrag, v);
}
// lgkmcnt(0)-only wait (vmcnt/expcnt bits all-ones), wave-local
__device__ __forceinline__ void lds_fence_wave() {
    __builtin_amdgcn_wave_barrier();
    __builtin_amdgcn_s_waitcnt(0xc07f);
    __builtin_amdgcn_wave_barrier();
}

// ---------------------------------------------------------------------------
// SINGLE-DISPATCH, HIGH-OCCUPANCY register-prefetch kernel.
// (Resubmission of round-6 kernel: that bench died on container acquisition,
// not on the kernel — zero information gained, experiment unchanged.)
//
// Evidence trail:
//   - Delivered BW at 5-9 effective waves/CU: pinned 2.34 TB/s (r0/r2/r4/r5);
//     all pipes <10%, L3-warm dispatch identical -> latency-bound, not HBM.
//   - r5 DMA double-buffer (loads fully pipelined): NULL -> per-wave
//     pipelining is not the lever.
//   - r1 at 17 resident waves/CU delivered 3.0 TB/s total; its +131 MB
//     traffic was VGPR-spill scratch (36 regs vs 52 needed), which also
//     explains the slowdown. So the path can move >=3.0 TB/s; the only
//     clean lever left is MORE RESIDENT WAVES with NO spills.
//   - launch_bounds(256,N) caps VGPR at ~256/N (r1: N=7 -> 36). Keep N=4
//     (cap 64 = the 8-waves/SIMD boundary); this kernel compiles to ~52-64.
//
// Geometry: LDS 22016 B/block -> 7 blocks/CU resident (28 waves/CU);
// grid 2048 blocks = 8192 waves x exactly 2 tiles each (excess blocks queue).
// Rare path reads x from GLOBAL (original fixup's exact numerics) and reuses
// hbuf for the exact hidden vector -> no extra LDS vs r2.
// ---------------------------------------------------------------------------
__global__ __launch_bounds__(256, 4)
void dyn_main(const float* __restrict__ x, const float* __restrict__ W1,
              const float* __restrict__ b1, const float* __restrict__ W2,
              const float* __restrict__ b2, const float* __restrict__ Wf,
              const float* __restrict__ bf, float* __restrict__ out,
              int ntiles)
{
    // weight fragments pre-gathered in lane order -> conflict-free b128 reads
    __shared__ __align__(16) short w2f[8][64][8];   // [ks*2+nb][lane][j]
    __shared__ __align__(16) short wff[8][64][8];   // [mb][lane][j]
    __shared__ __align__(16) float bfl[128];
    __shared__ __align__(16) short hbuf[4][16 * 40]; // per-wave H, stride 40
    // total: 8192 + 8192 + 512 + 5120 = 22016 B -> 7 blocks/CU

    const int tid  = threadIdx.x;
    const int wave = tid >> 6, lane = tid & 63;
    const int l15  = lane & 15, q = lane >> 4;

    // ---- stage weights into LDS (once per block) ----
    for (int idx = tid; idx < 4096; idx += 256) {
        const int j = idx & 7, ln = (idx >> 3) & 63, blk = idx >> 9;
        // W2 frag: blk = ks*2+nb ; element W2[nb*16 + (ln&15)][ks*32 + (ln>>4)*8 + j]
        const int ks = blk >> 1, nb = blk & 1;
        const int u = nb * 16 + (ln & 15);
        const int k = ks * 32 + ((ln >> 4) << 3) + j;
        ((short*)w2f)[idx] = (short)bf16s(W2[u * 128 + k]);
        // Wf frag: blk = mb ; element Wf[mb*16 + (ln&15)][(ln>>4)*8 + j], c < 32
        const int d = blk * 16 + (ln & 15);
        const int c = ((ln >> 4) << 3) + j;
        ((short*)wff)[idx] = (short)bf16s(Wf[d * 64 + c]);
    }
    for (int i = tid; i < 128; i += 256) bfl[i] = bf[i];
    const float b2r0 = b2[l15], b2r1 = b2[16 + l15];
    __syncthreads();

    // ones-column B fragment: B[k][n] = (n==0) ? 1.0bf16 : 0
    const unsigned ov = (l15 == 0) ? 0x3f803f80u : 0u;
    const bfrag onesf = mkfrag(ov, ov, ov, ov);

    const int wid = blockIdx.x * 4 + wave;
    const int wstride = gridDim.x * 4;

    long long cur = wid;
    bool more = cur < ntiles;
    floatx4 xl[8];
    if (more) {
        const float* base = x + cur * 2048 + l15 * 128 + q * 8;
        #pragma unroll
        for (int ks = 0; ks < 4; ++ks) {
            xl[2 * ks]     = *(const floatx4*)(base + ks * 32);
            xl[2 * ks + 1] = *(const floatx4*)(base + ks * 32 + 4);
        }
    }

    while (more) {
        const long long nxt = cur + wstride;
        const bool hasnxt = nxt < ntiles;
        floatx4 xc[8];
        #pragma unroll
        for (int i = 0; i < 8; ++i) xc[i] = xl[i];
        if (hasnxt) {   // register prefetch of next tile (kept in flight)
            const float* base = x + nxt * 2048 + l15 * 128 + q * 8;
            #pragma unroll
            for (int ks = 0; ks < 4; ++ks) {
                xl[2 * ks]     = *(const floatx4*)(base + ks * 32);
                xl[2 * ks + 1] = *(const floatx4*)(base + ks * 32 + 4);
            }
        }

        // ---- stage 1 ----
        floatx4 a0 = {0.f, 0.f, 0.f, 0.f}, a1 = a0, asum = a0;
        #pragma unroll
        for (int ks = 0; ks < 4; ++ks) {
            const floatx4 p = xc[2 * ks], r = xc[2 * ks + 1];
            const unsigned u0 = bf16pk(p[0], p[1]), u1 = bf16pk(p[2], p[3]);
            const unsigned u2 = bf16pk(r[0], r[1]), u3 = bf16pk(r[2], r[3]);
            const bfrag af = mkfrag(u0, u1, u2, u3);
            const bfrag aa = mkfrag(u0 & 0x7fff7fffu, u1 & 0x7fff7fffu,
                                    u2 & 0x7fff7fffu, u3 & 0x7fff7fffu);
            const bfrag w0 = *(const bfrag*)&w2f[ks * 2 + 0][lane][0];
            const bfrag w1 = *(const bfrag*)&w2f[ks * 2 + 1][lane][0];
            a0   = __builtin_amdgcn_mfma_f32_16x16x32_bf16(af, w0, a0, 0, 0, 0);
            a1   = __builtin_amdgcn_mfma_f32_16x16x32_bf16(af, w1, a1, 0, 0, 0);
            asum = __builtin_amdgcn_mfma_f32_16x16x32_bf16(aa, onesf, asum, 0, 0, 0);
        }

        // ---- flag suspicious rows: wave-uniform 16-bit row mask ----
        // abs-sums live in col 0 of asum -> lanes with l15==0, row = q*4+reg
        unsigned rowmask = 0;
        #pragma unroll
        for (int reg = 0; reg < 4; ++reg) {
            const unsigned long long bm =
                __ballot(l15 == 0 && asum[reg] > FLAG_THRESH);
            rowmask |= (unsigned)( bm        & 1ull) << (0 + reg);
            rowmask |= (unsigned)((bm >> 16) & 1ull) << (4 + reg);
            rowmask |= (unsigned)((bm >> 32) & 1ull) << (8 + reg);
            rowmask |= (unsigned)((bm >> 48) & 1ull) << (12 + reg);
        }

        // H = relu(S + b2) -> LDS bf16.  C-layout: row=q*4+reg, col=nb*16+l15
        short* hb = &hbuf[wave][0];
        #pragma unroll
        for (int reg = 0; reg < 4; ++reg) {
            const int row = q * 4 + reg;
            hb[row * 40 + l15]      = (short)bf16s(fmaxf(a0[reg] + b2r0, 0.f));
            hb[row * 40 + 16 + l15] = (short)bf16s(fmaxf(a1[reg] + b2r1, 0.f));
        }

        lds_fence_wave();

        // ---- stage 2 (transposed): A = Wf slice, B = H^T ----
        const bfrag hfrag = *(const bfrag*)&hb[l15 * 40 + q * 8];
        floatx4 o[8];
        #pragma unroll
        for (int mb = 0; mb < 8; ++mb) o[mb] = (floatx4){0.f, 0.f, 0.f, 0.f};
        #pragma unroll
        for (int mb = 0; mb < 8; ++mb) {
            const bfrag wfr = *(const bfrag*)&wff[mb][lane][0];
            o[mb] = __builtin_amdgcn_mfma_f32_16x16x32_bf16(wfr, hfrag, o[mb], 0, 0, 0);
        }

        // ---- store approx result for ALL rows (r0's proven store path) ----
        // C-layout: lane holds out[row = cur*16 + l15][d = mb*16 + q*4 + reg]
        float* obase = out + (cur * 16 + l15) * 128 + q * 4;
        #pragma unroll
        for (int mb = 0; mb < 8; ++mb) {
            const floatx4 bv = *(const floatx4*)&bfl[mb * 16 + q * 4];
            const floatx4 v = o[mb] + bv;
            *(floatx4*)(obase + mb * 16) = v;
        }

        // ---- rare path (~35/16384 tiles): exact fp32 recompute + overwrite.
        // x re-read from GLOBAL (identical load/op order to the original
        // 2-kernel fixup -> bit-identical results). hbuf reused as the
        // exact hidden vector (stage 2 has already consumed hfrag).
        if (__builtin_expect(rowmask != 0, 0)) {
            __builtin_amdgcn_s_waitcnt(0x0F70);  // approx stores committed
            float* hw = (float*)&hbuf[wave][0];
            unsigned mm = rowmask;
            while (mm) {
                const int r = (int)__builtin_ctz(mm); mm &= mm - 1;
                const float* xrow = x + (cur * 16 + r) * 128;
                const float2 xv = *(const float2*)&xrow[lane * 2];
                float s = fabsf(xv.x) + fabsf(xv.y);
                #pragma unroll
                for (int d = 1; d < 64; d <<= 1) s += __shfl_xor(s, d);
                float hv = 0.f;
                if (s > 128.0f) {                    // branch 1: 64 units of W1
                    float a = 0.f;
                    for (int k = 0; k < 128; k += 4) {
                        const float4 qq = *(const float4*)&xrow[k];
                        const float4 wv = *(const float4*)&W1[lane * 128 + k];
                        a = fmaf(qq.x, wv.x, a); a = fmaf(qq.y, wv.y, a);
                        a = fmaf(qq.z, wv.z, a); a = fmaf(qq.w, wv.w, a);
                    }
                    hv = fmaxf(a + b1[lane], 0.f);
                } else if (lane < 32) {              // branch 2: 32 units of W2
                    float a = 0.f;
                    for (int k = 0; k < 128; k += 4) {
                        const float4 qq = *(const float4*)&xrow[k];
                        const float4 wv = *(const float4*)&W2[lane * 128 + k];
                        a = fmaf(qq.x, wv.x, a); a = fmaf(qq.y, wv.y, a);
                        a = fmaf(qq.z, wv.z, a); a = fmaf(qq.w, wv.w, a);
                    }
                    hv = fmaxf(a + b2[lane], 0.f);
                }
                hw[lane] = hv;                       // zero-padded for branch 2
                lds_fence_wave();
                #pragma unroll
                for (int jj = 0; jj < 2; ++jj) {
                    const int d = lane + 64 * jj;
                    float a = bf[d];
                    for (int u = 0; u < 64; ++u)
                        a = fmaf(hw[u], Wf[d * 64 + u], a);
                    out[(cur * 16 + r) * 128 + d] = a;
                }
                lds_fence_wave();   // hw reads drained before next row reuse
            }
        }

        lds_fence_wave();   // hfrag read drained before next iter's H writes
        cur = nxt; more = hasnxt;
    }
}

extern "C" void kernel_launch(void* const* d_in, const int* in_sizes, int n_in,
                              void* d_out, int out_size, void* d_ws, size_t ws_size,
                              hipStream_t stream) {
    const float* x  = (const float*)d_in[0];
    const float* W1 = (const float*)d_in[1];
    const float* b1 = (const float*)d_in[2];
    const float* W2 = (const float*)d_in[3];
    const float* b2 = (const float*)d_in[4];
    const float* Wf = (const float*)d_in[5];
    const float* bf = (const float*)d_in[6];
    float* out = (float*)d_out;
    (void)d_ws; (void)ws_size;

    const int B = in_sizes[0] / 128;   // D = 128
    const int ntiles = B / 16;         // 16384 for B=262144

    // ONE dispatch. Grid sized from work: min(2048, ceil(ntiles/4)) blocks.
    // At B=262144: 2048 blocks x 256 thr = 8192 waves x exactly 2 tiles.
    // LDS 22016 B -> 7 blocks/CU RESIDENT (28 waves/CU); VGPR cap 64 via
    // launch_bounds(256,4) keeps 8-waves/SIMD eligibility with NO spills
    // (r1's regression was spill scratch at VGPR=36, not L2 thrash).
    int nblk = (ntiles + 3) / 4;
    if (nblk > 2048) nblk = 2048;
    if (nblk < 1) nblk = 1;
    hipLaunchKernelGGL(dyn_main, dim3(nblk), dim3(256), 0, stream,
                       x, W1, b1, W2, b2, Wf, bf, out, ntiles);
}